// Round 21
// baseline (175.948 us; speedup 1.0000x reference)
//
#include <hip/hip_runtime.h>
#include <hip/hip_bf16.h>

#define BB 128
#define NN 512
#define DD 256

typedef __attribute__((ext_vector_type(4))) float f32x4;
typedef __attribute__((ext_vector_type(8))) short s16x8;
typedef __attribute__((ext_vector_type(8))) __bf16 bf16x8;

static __device__ __forceinline__ bf16x8 as_bf(s16x8 v) {
  return __builtin_bit_cast(bf16x8, v);
}

static __device__ __forceinline__ unsigned short f2bf(float f) {
  unsigned u = __builtin_bit_cast(unsigned, f);
  u += 0x7FFFu + ((u >> 16) & 1u);
  return (unsigned short)(u >> 16);
}

// tanh-form GELU: h*(1 - rcp(exp(1.5957691*h*(1+0.044715*h^2)) + 1))
static __device__ __forceinline__ float gelu_fast(float h) {
  float z = 1.5957691216057308f * h * (1.0f + 0.044715f * h * h);
  float e = __expf(z);
  float r = __builtin_amdgcn_rcpf(e + 1.0f);
  return h - h * r;
}

__device__ __forceinline__ float wave_sum(float v) {
#pragma unroll
  for (int o = 32; o > 0; o >>= 1) v += __shfl_xor(v, o);
  return v;
}

__global__ void k_init(int* wsi) {
  if (threadIdx.x < 8) wsi[threadIdx.x] = 0;
}

__global__ void k_counts(const int* __restrict__ msk, int* __restrict__ wsi) {
  const int b = blockIdx.x;
  int cnt = 0;
  for (int i = threadIdx.x; i < NN; i += blockDim.x) cnt += (msk[b * NN + i] != 0) ? 1 : 0;
  float s = wave_sum((float)cnt);
  __shared__ float red[4];
  const int lane = threadIdx.x & 63, wv = threadIdx.x >> 6;
  if (lane == 0) red[wv] = s;
  __syncthreads();
  if (threadIdx.x == 0) {
    int k = (int)(red[0] + red[1] + red[2] + red[3] + 0.5f);
    atomicAdd(&wsi[4], k);
    atomicAdd(&wsi[5], NN * NN - (NN - k) * (NN - k));
  }
}

// transpose + bf16-convert the weight matrices into workspace
__global__ void k_prep(const float* __restrict__ Wc, const float* __restrict__ Wt1,
                       const float* __restrict__ Ws1, const float* __restrict__ Wt2,
                       const float* __restrict__ Ws2,
                       unsigned short* __restrict__ WcT, unsigned short* __restrict__ Wt1T,
                       unsigned short* __restrict__ Ws1T, unsigned short* __restrict__ Wt2T,
                       unsigned short* __restrict__ Ws2T) {
  int t = blockIdx.x * 256 + threadIdx.x;  // 0..65535
  int c = t >> 8, d = t & 255;
  WcT [c * 256 + d] = f2bf(Wc [d * 256 + c]);
  Wt1T[c * 256 + d] = f2bf(Wt1[d * 256 + c]);
  Ws1T[c * 256 + d] = f2bf(Ws1[d * 256 + c]);
  if (c < 16) {
    Wt2T[c * 256 + d] = (c < 6) ? f2bf(Wt2[d * 6 + c]) : (unsigned short)0;
    Ws2T[c * 256 + d] = (c < 8) ? f2bf(Ws2[d * 8 + c]) : (unsigned short)0;
  }
}

// ---------------- heads: 128 rows/block, 512 threads, dual-head fused K-loop ----------------
// r17 structure + W2 tiles staged ONCE during phase 0 into dedicated buffers (overlaps the
// K-loop; removes one barrier + serialized stage per head). LDS 92.4 KB (same 1-blk/CU regime).
__global__ __launch_bounds__(512) void k_heads(
    const float* __restrict__ x, unsigned short* __restrict__ xbf,
    const int* __restrict__ msk,
    const int* __restrict__ tgt, const float* __restrict__ stats,
    const unsigned short* __restrict__ Wt1T, const unsigned short* __restrict__ Ws1T,
    const unsigned short* __restrict__ Wt2T, const unsigned short* __restrict__ Ws2T,
    const float* __restrict__ bt1, const float* __restrict__ bs1,
    const float* __restrict__ gt, const float* __restrict__ gs,
    const float* __restrict__ blt, const float* __restrict__ bls,
    const float* __restrict__ bt2, const float* __restrict__ bs2,
    float* __restrict__ fs)
{
  const int tid = threadIdx.x;
  const int lane = tid & 63, w = tid >> 6;
  const int wm = w & 1, wn = w >> 1;       // 2 x 4 wave grid over 128 x 256
  const int fr = lane & 15, fg = lane >> 4;
  const int row0 = blockIdx.x * 128;

  __shared__ __align__(16) unsigned short lds_x[128 * 264];   // 67,584 B; becomes h tile later
  __shared__ __align__(16) unsigned short lds_w2t[16 * 264];  // 8,448 B (staged once)
  __shared__ __align__(16) unsigned short lds_w2s[16 * 264];  // 8,448 B (staged once)
  __shared__ float red[128 * 8];                              // 4,096 B
  __shared__ float lg[128 * 8];                               // 4,096 B
  unsigned short* lds_h = lds_x;           // alias: x dead after the dual K-loop

  // ---- phase 0: stage x-tile (fp32 -> bf16 pack -> LDS + xbf) AND both W2 tiles ----
#pragma unroll
  for (int p = 0; p < 8; ++p) {
    int c = tid + p * 512;             // 0..4095 chunks of 8 elems
    int r = c >> 5, ch = c & 31;
    const float4* s = (const float4*)&x[(size_t)(row0 + r) * DD + ch * 8];
    float4 v0 = s[0], v1 = s[1];
    uint4 pk;
    pk.x = (unsigned)f2bf(v0.x) | ((unsigned)f2bf(v0.y) << 16);
    pk.y = (unsigned)f2bf(v0.z) | ((unsigned)f2bf(v0.w) << 16);
    pk.z = (unsigned)f2bf(v1.x) | ((unsigned)f2bf(v1.y) << 16);
    pk.w = (unsigned)f2bf(v1.z) | ((unsigned)f2bf(v1.w) << 16);
    *(uint4*)&lds_x[r * 264 + ch * 8] = pk;
    *(uint4*)&xbf[(size_t)(row0 + r) * DD + ch * 8] = pk;
  }
  {
    int r = tid >> 5, ch = tid & 31;   // 512 threads = 16 rows x 32 chunks
    *(uint4*)&lds_w2t[r * 264 + ch * 8] = *(const uint4*)&Wt2T[r * 256 + ch * 8];
    *(uint4*)&lds_w2s[r * 264 + ch * 8] = *(const uint4*)&Ws2T[r * 256 + ch * 8];
  }
  __syncthreads();

  // ---- dual-head K-loop: A-frags read once, both weight streams in flight ----
  f32x4 at[4][4], asx[4][4];
#pragma unroll
  for (int i = 0; i < 4; ++i)
#pragma unroll
    for (int j = 0; j < 4; ++j) {
      at[i][j]  = f32x4{0.f, 0.f, 0.f, 0.f};
      asx[i][j] = f32x4{0.f, 0.f, 0.f, 0.f};
    }

#pragma unroll
  for (int ks = 0; ks < 8; ++ks) {
    const int ko = ks * 32 + fg * 8;
    s16x8 af[4], bt_[4], bs_[4];
#pragma unroll
    for (int i = 0; i < 4; ++i)
      af[i] = *(const s16x8*)&lds_x[(wm * 64 + i * 16 + fr) * 264 + ko];
#pragma unroll
    for (int j = 0; j < 4; ++j) {
      bt_[j] = *(const s16x8*)&Wt1T[(size_t)(wn * 64 + j * 16 + fr) * DD + ko];
      bs_[j] = *(const s16x8*)&Ws1T[(size_t)(wn * 64 + j * 16 + fr) * DD + ko];
    }
#pragma unroll
    for (int i = 0; i < 4; ++i)
#pragma unroll
      for (int j = 0; j < 4; ++j) {
        at[i][j]  = __builtin_amdgcn_mfma_f32_16x16x32_bf16(as_bf(af[i]), as_bf(bt_[j]), at[i][j], 0, 0, 0);
        asx[i][j] = __builtin_amdgcn_mfma_f32_16x16x32_bf16(as_bf(af[i]), as_bf(bs_[j]), asx[i][j], 0, 0, 0);
      }
  }

  // ===================== head 0 epilogue (acc = at) =====================
  {
    float sA[16], qA[16];
#pragma unroll
    for (int k = 0; k < 16; ++k) { sA[k] = 0.f; qA[k] = 0.f; }
#pragma unroll
    for (int i = 0; i < 4; ++i)
#pragma unroll
      for (int j = 0; j < 4; ++j) {
        int col = wn * 64 + j * 16 + fr;
        float bb = bt1[col];
#pragma unroll
        for (int r = 0; r < 4; ++r) {
          float h = gelu_fast(at[i][j][r] + bb);
          at[i][j][r] = h;
          sA[i * 4 + r] += h;
          qA[i * 4 + r] += h * h;
        }
      }
#pragma unroll
    for (int o = 1; o < 16; o <<= 1) {
#pragma unroll
      for (int k = 0; k < 16; ++k) {
        sA[k] += __shfl_xor(sA[k], o);
        qA[k] += __shfl_xor(qA[k], o);
      }
    }
    if (fr == 0) {
#pragma unroll
      for (int i = 0; i < 4; ++i)
#pragma unroll
        for (int r = 0; r < 4; ++r) {
          int row = wm * 64 + i * 16 + fg * 4 + r;
          red[row * 8 + wn]     = sA[i * 4 + r];
          red[row * 8 + 4 + wn] = qA[i * 4 + r];
        }
    }
    __syncthreads();   // red visible; also fences K-loop's last lds_x reads before h-writes
#pragma unroll
    for (int i = 0; i < 4; ++i)
#pragma unroll
      for (int r = 0; r < 4; ++r) {
        int row = wm * 64 + i * 16 + fg * 4 + r;
        float s = red[row * 8 + 0] + red[row * 8 + 1] + red[row * 8 + 2] + red[row * 8 + 3];
        float q = red[row * 8 + 4] + red[row * 8 + 5] + red[row * 8 + 6] + red[row * 8 + 7];
        float mu = s * (1.0f / DD);
        float var = q * (1.0f / DD) - mu * mu;
        float rstd = rsqrtf(var + 1e-5f);
#pragma unroll
        for (int j = 0; j < 4; ++j) {
          int col = wn * 64 + j * 16 + fr;
          float hn = (at[i][j][r] - mu) * rstd * gt[col] + blt[col];
          lds_h[row * 264 + col] = f2bf(hn);
        }
      }
    __syncthreads();   // h visible (W2 already resident since phase 0)
    {
      f32x4 a1 = f32x4{0.f, 0.f, 0.f, 0.f};
#pragma unroll
      for (int ks = 0; ks < 8; ++ks) {
        s16x8 av = *(const s16x8*)&lds_h[(w * 16 + fr) * 264 + ks * 32 + fg * 8];
        s16x8 bv = *(const s16x8*)&lds_w2t[fr * 264 + ks * 32 + fg * 8];
        a1 = __builtin_amdgcn_mfma_f32_16x16x32_bf16(as_bf(av), as_bf(bv), a1, 0, 0, 0);
      }
      if (fr < 8) {
#pragma unroll
        for (int r = 0; r < 4; ++r) lg[(w * 16 + fg * 4 + r) * 8 + fr] = a1[r];
      }
    }
    __syncthreads();
    if (tid < 128) {
      int grow = row0 + tid;
      int mbit = msk[grow];
      float l[6], mx = -1e30f;
#pragma unroll
      for (int c = 0; c < 6; ++c) { l[c] = lg[tid * 8 + c] + bt2[c]; mx = fmaxf(mx, l[c]); }
      float se = 0.0f;
#pragma unroll
      for (int c = 0; c < 6; ++c) se += expf(l[c] - mx);
      float lse = mx + logf(se);
      int t = tgt[grow];
      float lt = 0.0f;
#pragma unroll
      for (int c = 0; c < 6; ++c) lt = (c == t) ? l[c] : lt;
      float contrib = mbit ? (lse - lt) : 0.0f;
      float s = wave_sum(contrib);
      if ((tid & 63) == 0) atomicAdd(&fs[0], s);
    }
    __syncthreads();
  }

  // ===================== head 1 epilogue (acc = asx) =====================
  {
    float sA[16], qA[16];
#pragma unroll
    for (int k = 0; k < 16; ++k) { sA[k] = 0.f; qA[k] = 0.f; }
#pragma unroll
    for (int i = 0; i < 4; ++i)
#pragma unroll
      for (int j = 0; j < 4; ++j) {
        int col = wn * 64 + j * 16 + fr;
        float bb = bs1[col];
#pragma unroll
        for (int r = 0; r < 4; ++r) {
          float h = gelu_fast(asx[i][j][r] + bb);
          asx[i][j][r] = h;
          sA[i * 4 + r] += h;
          qA[i * 4 + r] += h * h;
        }
      }
#pragma unroll
    for (int o = 1; o < 16; o <<= 1) {
#pragma unroll
      for (int k = 0; k < 16; ++k) {
        sA[k] += __shfl_xor(sA[k], o);
        qA[k] += __shfl_xor(qA[k], o);
      }
    }
    if (fr == 0) {
#pragma unroll
      for (int i = 0; i < 4; ++i)
#pragma unroll
        for (int r = 0; r < 4; ++r) {
          int row = wm * 64 + i * 16 + fg * 4 + r;
          red[row * 8 + wn]     = sA[i * 4 + r];
          red[row * 8 + 4 + wn] = qA[i * 4 + r];
        }
    }
    __syncthreads();
#pragma unroll
    for (int i = 0; i < 4; ++i)
#pragma unroll
      for (int r = 0; r < 4; ++r) {
        int row = wm * 64 + i * 16 + fg * 4 + r;
        float s = red[row * 8 + 0] + red[row * 8 + 1] + red[row * 8 + 2] + red[row * 8 + 3];
        float q = red[row * 8 + 4] + red[row * 8 + 5] + red[row * 8 + 6] + red[row * 8 + 7];
        float mu = s * (1.0f / DD);
        float var = q * (1.0f / DD) - mu * mu;
        float rstd = rsqrtf(var + 1e-5f);
#pragma unroll
        for (int j = 0; j < 4; ++j) {
          int col = wn * 64 + j * 16 + fr;
          float hn = (asx[i][j][r] - mu) * rstd * gs[col] + bls[col];
          lds_h[row * 264 + col] = f2bf(hn);
        }
      }
    __syncthreads();
    {
      f32x4 a1 = f32x4{0.f, 0.f, 0.f, 0.f};
#pragma unroll
      for (int ks = 0; ks < 8; ++ks) {
        s16x8 av = *(const s16x8*)&lds_h[(w * 16 + fr) * 264 + ks * 32 + fg * 8];
        s16x8 bv = *(const s16x8*)&lds_w2s[fr * 264 + ks * 32 + fg * 8];
        a1 = __builtin_amdgcn_mfma_f32_16x16x32_bf16(as_bf(av), as_bf(bv), a1, 0, 0, 0);
      }
      if (fr < 8) {
#pragma unroll
        for (int r = 0; r < 4; ++r) lg[(w * 16 + fg * 4 + r) * 8 + fr] = a1[r];
      }
    }
    __syncthreads();
    if (tid < 128) {
      int grow = row0 + tid;
      int mbit = msk[grow];
      const float* st = stats + (size_t)grow * 8;
      float sse = 0.0f;
#pragma unroll
      for (int c = 0; c < 8; ++c) {
        float d = (lg[tid * 8 + c] + bs2[c]) - st[c];
        sse += d * d;
      }
      float contrib = mbit ? sse : 0.0f;
      float s = wave_sum(contrib);
      if ((tid & 63) == 0) atomicAdd(&fs[1], s);
    }
  }
}

// ---------------- correlation: 64-row i-tiles, ~79 KB LDS (r17-verbatim, green) ----------------
__global__ __launch_bounds__(512) void k_corr(
    const unsigned short* __restrict__ xbf, const int* __restrict__ msk,
    const float* __restrict__ corr, const unsigned short* __restrict__ WcT,
    const float* __restrict__ bcp, float* __restrict__ fs)
{
  const int tid = threadIdx.x;
  const int b  = blockIdx.x >> 3;
  const int it = blockIdx.x & 7;
  const int i0 = it * 64;
  const int lane = tid & 63, w = tid >> 6;   // 8 waves; wave w owns 32 output cols
  const int wn = w;
  const int fr = lane & 15, fg = lane >> 4;

  __shared__ __align__(16) unsigned short lds_y[64 * 264];   // 33792 B
  __shared__ __align__(16) unsigned short lds_a[64 * 72];    //  9216 B
  __shared__ __align__(16) unsigned short lds_b[256 * 72];   // 36864 B
  __shared__ int ms_i[64];
  __shared__ int ms_j[256];
  __shared__ float red8[8];

  const unsigned short* xb = xbf + (size_t)b * NN * DD;

  // ---- phase Y: y = x[i0..i0+63] @ Wc ----
  f32x4 acc[4][2];
#pragma unroll
  for (int i = 0; i < 4; ++i)
#pragma unroll
    for (int j = 0; j < 2; ++j) acc[i][j] = f32x4{0.f, 0.f, 0.f, 0.f};

  for (int kt = 0; kt < 4; ++kt) {
    __syncthreads();
    {
      int r = tid >> 3, ch = tid & 7;
      *(uint4*)&lds_a[r * 72 + ch * 8] = *(const uint4*)&xb[(size_t)(i0 + r) * DD + kt * 64 + ch * 8];
    }
#pragma unroll
    for (int p = 0; p < 4; ++p) {
      int idx = tid + p * 512;
      int r = idx >> 3, ch = idx & 7;
      *(uint4*)&lds_b[r * 72 + ch * 8] = *(const uint4*)&WcT[r * 256 + kt * 64 + ch * 8];
    }
    __syncthreads();
#pragma unroll
    for (int ks = 0; ks < 2; ++ks) {
      s16x8 af[4], bfv[2];
#pragma unroll
      for (int i = 0; i < 4; ++i)
        af[i] = *(const s16x8*)&lds_a[(i * 16 + fr) * 72 + ks * 32 + fg * 8];
#pragma unroll
      for (int j = 0; j < 2; ++j)
        bfv[j] = *(const s16x8*)&lds_b[(wn * 32 + j * 16 + fr) * 72 + ks * 32 + fg * 8];
#pragma unroll
      for (int i = 0; i < 4; ++i)
#pragma unroll
        for (int j = 0; j < 2; ++j)
          acc[i][j] = __builtin_amdgcn_mfma_f32_16x16x32_bf16(as_bf(af[i]), as_bf(bfv[j]), acc[i][j], 0, 0, 0);
    }
  }
#pragma unroll
  for (int i = 0; i < 4; ++i)
#pragma unroll
    for (int j = 0; j < 2; ++j)
#pragma unroll
      for (int r = 0; r < 4; ++r) {
        int row = i * 16 + fg * 4 + r;
        int col = wn * 32 + j * 16 + fr;
        lds_y[row * 264 + col] = f2bf(acc[i][j][r]);
      }
  if (tid < 64) ms_i[tid] = msk[b * NN + i0 + tid];

  // ---- phase S: scores = y @ x^T, fused tanh + masked MSE ----
  const float bc = bcp[0];
  const float* tb = corr + (size_t)b * NN * NN;
  float sse = 0.0f;

  for (int jc = 0; jc < 2; ++jc) {
    const int j0 = jc * 256;
#pragma unroll
    for (int i = 0; i < 4; ++i)
#pragma unroll
      for (int j = 0; j < 2; ++j) acc[i][j] = f32x4{0.f, 0.f, 0.f, 0.f};

    for (int kt = 0; kt < 4; ++kt) {
      __syncthreads();
#pragma unroll
      for (int p = 0; p < 4; ++p) {
        int idx = tid + p * 512;
        int r = idx >> 3, ch = idx & 7;
        *(uint4*)&lds_b[r * 72 + ch * 8] = *(const uint4*)&xb[(size_t)(j0 + r) * DD + kt * 64 + ch * 8];
      }
      if (kt == 0 && tid < 256) ms_j[tid] = msk[b * NN + j0 + tid];
      __syncthreads();
#pragma unroll
      for (int ks = 0; ks < 2; ++ks) {
        s16x8 af[4], bfv[2];
#pragma unroll
        for (int i = 0; i < 4; ++i)
          af[i] = *(const s16x8*)&lds_y[(i * 16 + fr) * 264 + kt * 64 + ks * 32 + fg * 8];
#pragma unroll
        for (int j = 0; j < 2; ++j)
          bfv[j] = *(const s16x8*)&lds_b[(wn * 32 + j * 16 + fr) * 72 + ks * 32 + fg * 8];
#pragma unroll
        for (int i = 0; i < 4; ++i)
#pragma unroll
          for (int j = 0; j < 2; ++j)
            acc[i][j] = __builtin_amdgcn_mfma_f32_16x16x32_bf16(as_bf(af[i]), as_bf(bfv[j]), acc[i][j], 0, 0, 0);
      }
    }

    // late batched register prefetch of the 32 corr targets for this jc tile
    float tg[4][2][4];
#pragma unroll
    for (int i = 0; i < 4; ++i) {
      int rbase = i0 + i * 16 + fg * 4;
#pragma unroll
      for (int j = 0; j < 2; ++j) {
        int gj = j0 + wn * 32 + j * 16 + fr;
#pragma unroll
        for (int r = 0; r < 4; ++r)
          tg[i][j][r] = tb[(size_t)(rbase + r) * NN + gj];
      }
    }

    // compute epilogue on registers
#pragma unroll
    for (int i = 0; i < 4; ++i) {
      int rbase = i * 16 + fg * 4;
#pragma unroll
      for (int j = 0; j < 2; ++j) {
        int colc = wn * 32 + j * 16 + fr;
        int gj = j0 + colc;
        int mj = ms_j[colc];
#pragma unroll
        for (int r = 0; r < 4; ++r) {
          int gi = i0 + rbase + r;
          float s = acc[i][j][r] + bc;
          float e = __expf(2.0f * s);
          float cv = 1.0f - 2.0f * __builtin_amdgcn_rcpf(e + 1.0f);
          if (gi == gj) cv = 1.0f;
          float d = cv - tg[i][j][r];
          int mb = ms_i[rbase + r] | mj;
          sse += mb ? d * d : 0.0f;
        }
      }
    }
  }

  float s = wave_sum(sse);
  if (lane == 0) red8[w] = s;
  __syncthreads();
  if (tid == 0) {
    float t = 0.f;
#pragma unroll
    for (int i = 0; i < 8; ++i) t += red8[i];
    atomicAdd(&fs[2], t);
  }
}

__global__ void k_final(const float* __restrict__ fs, const int* __restrict__ wsi,
                        float* __restrict__ out) {
  if (threadIdx.x == 0 && blockIdx.x == 0) {
    float cm = (float)wsi[4];
    float c2 = (float)wsi[5];
    out[0] = fs[0] / fmaxf(cm, 1.0f) + fs[1] / fmaxf(8.0f * cm, 1.0f) +
             0.5f * fs[2] / fmaxf(c2, 1.0f);
  }
}

extern "C" void kernel_launch(void* const* d_in, const int* in_sizes, int n_in,
                              void* d_out, int out_size, void* d_ws, size_t ws_size,
                              hipStream_t stream) {
  const float* x     = (const float*)d_in[0];
  const int*   msk   = (const int*)d_in[1];
  const int*   tgt   = (const int*)d_in[2];
  const float* stats = (const float*)d_in[3];
  const float* corr  = (const float*)d_in[4];
  const float* Wt1   = (const float*)d_in[5];
  const float* bt1   = (const float*)d_in[6];
  const float* gt    = (const float*)d_in[7];
  const float* blt   = (const float*)d_in[8];
  const float* Wt2   = (const float*)d_in[9];
  const float* bt2   = (const float*)d_in[10];
  const float* Ws1   = (const float*)d_in[11];
  const float* bs1   = (const float*)d_in[12];
  const float* gs    = (const float*)d_in[13];
  const float* bls   = (const float*)d_in[14];
  const float* Ws2   = (const float*)d_in[15];
  const float* bs2   = (const float*)d_in[16];
  const float* Wc    = (const float*)d_in[17];
  const float* bc    = (const float*)d_in[18];

  float* fs = (float*)d_ws;
  int* wsi  = (int*)d_ws;
  unsigned short* WcT  = (unsigned short*)((char*)d_ws + 256);
  unsigned short* Wt1T = WcT + 65536;
  unsigned short* Ws1T = Wt1T + 65536;
  unsigned short* Wt2T = Ws1T + 65536;
  unsigned short* Ws2T = Wt2T + 4096;
  unsigned short* xbf  = Ws2T + 4096;   // 32 MB; total ws use ~34 MB

  hipLaunchKernelGGL(k_init, dim3(1), dim3(64), 0, stream, wsi);
  hipLaunchKernelGGL(k_counts, dim3(BB), dim3(256), 0, stream, msk, wsi);
  hipLaunchKernelGGL(k_prep, dim3(256), dim3(256), 0, stream,
                     Wc, Wt1, Ws1, Wt2, Ws2, WcT, Wt1T, Ws1T, Wt2T, Ws2T);
  hipLaunchKernelGGL(k_heads, dim3((BB * NN) / 128), dim3(512), 0, stream,
                     x, xbf, msk, tgt, stats, Wt1T, Ws1T, Wt2T, Ws2T,
                     bt1, bs1, gt, gs, blt, bls, bt2, bs2, fs);
  hipLaunchKernelGGL(k_corr, dim3(BB * (NN / 64)), dim3(512), 0, stream,
                     xbf, msk, corr, WcT, bc, fs);
  hipLaunchKernelGGL(k_final, dim3(1), dim3(64), 0, stream, fs, wsi, (float*)d_out);
}

// Round 22
// 172.707 us; speedup vs baseline: 1.0188x; 1.0188x over previous
//
#include <hip/hip_runtime.h>
#include <hip/hip_bf16.h>

#define BB 128
#define NN 512
#define DD 256

typedef __attribute__((ext_vector_type(4))) float f32x4;
typedef __attribute__((ext_vector_type(8))) short s16x8;
typedef __attribute__((ext_vector_type(8))) __bf16 bf16x8;

static __device__ __forceinline__ bf16x8 as_bf(s16x8 v) {
  return __builtin_bit_cast(bf16x8, v);
}

static __device__ __forceinline__ unsigned short f2bf(float f) {
  unsigned u = __builtin_bit_cast(unsigned, f);
  u += 0x7FFFu + ((u >> 16) & 1u);
  return (unsigned short)(u >> 16);
}

// tanh-form GELU: h*(1 - rcp(exp(1.5957691*h*(1+0.044715*h^2)) + 1))
static __device__ __forceinline__ float gelu_fast(float h) {
  float z = 1.5957691216057308f * h * (1.0f + 0.044715f * h * h);
  float e = __expf(z);
  float r = __builtin_amdgcn_rcpf(e + 1.0f);
  return h - h * r;
}

__device__ __forceinline__ float wave_sum(float v) {
#pragma unroll
  for (int o = 32; o > 0; o >>= 1) v += __shfl_xor(v, o);
  return v;
}

__global__ void k_init(int* wsi) {
  if (threadIdx.x < 8) wsi[threadIdx.x] = 0;
}

__global__ void k_counts(const int* __restrict__ msk, int* __restrict__ wsi) {
  const int b = blockIdx.x;
  int cnt = 0;
  for (int i = threadIdx.x; i < NN; i += blockDim.x) cnt += (msk[b * NN + i] != 0) ? 1 : 0;
  float s = wave_sum((float)cnt);
  __shared__ float red[4];
  const int lane = threadIdx.x & 63, wv = threadIdx.x >> 6;
  if (lane == 0) red[wv] = s;
  __syncthreads();
  if (threadIdx.x == 0) {
    int k = (int)(red[0] + red[1] + red[2] + red[3] + 0.5f);
    atomicAdd(&wsi[4], k);
    atomicAdd(&wsi[5], NN * NN - (NN - k) * (NN - k));
  }
}

// transpose + bf16-convert the weight matrices into workspace
__global__ void k_prep(const float* __restrict__ Wc, const float* __restrict__ Wt1,
                       const float* __restrict__ Ws1, const float* __restrict__ Wt2,
                       const float* __restrict__ Ws2,
                       unsigned short* __restrict__ WcT, unsigned short* __restrict__ Wt1T,
                       unsigned short* __restrict__ Ws1T, unsigned short* __restrict__ Wt2T,
                       unsigned short* __restrict__ Ws2T) {
  int t = blockIdx.x * 256 + threadIdx.x;  // 0..65535
  int c = t >> 8, d = t & 255;
  WcT [c * 256 + d] = f2bf(Wc [d * 256 + c]);
  Wt1T[c * 256 + d] = f2bf(Wt1[d * 256 + c]);
  Ws1T[c * 256 + d] = f2bf(Ws1[d * 256 + c]);
  if (c < 16) {
    Wt2T[c * 256 + d] = (c < 6) ? f2bf(Wt2[d * 6 + c]) : (unsigned short)0;
    Ws2T[c * 256 + d] = (c < 8) ? f2bf(Ws2[d * 8 + c]) : (unsigned short)0;
  }
}

// ---------------- heads: 128 rows/block, 512 threads, dual-head fused K-loop ----------------
// One K-loop computes BOTH heads (at/asx accumulators, 2x B-load ILP); lds_h aliases lds_x
// (dead after the K-loop) -> LDS 80.1 KB. Stages x fp32->bf16 and writes xbf (prep_x fused).
__global__ __launch_bounds__(512) void k_heads(
    const float* __restrict__ x, unsigned short* __restrict__ xbf,
    const int* __restrict__ msk,
    const int* __restrict__ tgt, const float* __restrict__ stats,
    const unsigned short* __restrict__ Wt1T, const unsigned short* __restrict__ Ws1T,
    const unsigned short* __restrict__ Wt2T, const unsigned short* __restrict__ Ws2T,
    const float* __restrict__ bt1, const float* __restrict__ bs1,
    const float* __restrict__ gt, const float* __restrict__ gs,
    const float* __restrict__ blt, const float* __restrict__ bls,
    const float* __restrict__ bt2, const float* __restrict__ bs2,
    float* __restrict__ fs)
{
  const int tid = threadIdx.x;
  const int lane = tid & 63, w = tid >> 6;
  const int wm = w & 1, wn = w >> 1;       // 2 x 4 wave grid over 128 x 256
  const int fr = lane & 15, fg = lane >> 4;
  const int row0 = blockIdx.x * 128;

  __shared__ __align__(16) unsigned short lds_x[128 * 264];   // 67,584 B; becomes h tile later
  __shared__ __align__(16) unsigned short pool2[4224];        // 8,448 B: w2 | red
  __shared__ float lg[128 * 8];                               // 4,096 B
  unsigned short* lds_h  = lds_x;          // alias: x dead after the dual K-loop
  unsigned short* lds_w2 = pool2;
  float* red = (float*)pool2;

  // ---- stage the FULL 128x256 x-tile once: fp32 -> bf16 pack -> LDS + xbf ----
#pragma unroll
  for (int p = 0; p < 8; ++p) {
    int c = tid + p * 512;             // 0..4095 chunks of 8 elems
    int r = c >> 5, ch = c & 31;
    const float4* s = (const float4*)&x[(size_t)(row0 + r) * DD + ch * 8];
    float4 v0 = s[0], v1 = s[1];
    uint4 pk;
    pk.x = (unsigned)f2bf(v0.x) | ((unsigned)f2bf(v0.y) << 16);
    pk.y = (unsigned)f2bf(v0.z) | ((unsigned)f2bf(v0.w) << 16);
    pk.z = (unsigned)f2bf(v1.x) | ((unsigned)f2bf(v1.y) << 16);
    pk.w = (unsigned)f2bf(v1.z) | ((unsigned)f2bf(v1.w) << 16);
    *(uint4*)&lds_x[r * 264 + ch * 8] = pk;
    *(uint4*)&xbf[(size_t)(row0 + r) * DD + ch * 8] = pk;
  }
  __syncthreads();

  // ---- dual-head K-loop: A-frags read once, both weight streams in flight ----
  f32x4 at[4][4], asx[4][4];
#pragma unroll
  for (int i = 0; i < 4; ++i)
#pragma unroll
    for (int j = 0; j < 4; ++j) {
      at[i][j]  = f32x4{0.f, 0.f, 0.f, 0.f};
      asx[i][j] = f32x4{0.f, 0.f, 0.f, 0.f};
    }

#pragma unroll
  for (int ks = 0; ks < 8; ++ks) {
    const int ko = ks * 32 + fg * 8;
    s16x8 af[4], bt_[4], bs_[4];
#pragma unroll
    for (int i = 0; i < 4; ++i)
      af[i] = *(const s16x8*)&lds_x[(wm * 64 + i * 16 + fr) * 264 + ko];
#pragma unroll
    for (int j = 0; j < 4; ++j) {
      bt_[j] = *(const s16x8*)&Wt1T[(size_t)(wn * 64 + j * 16 + fr) * DD + ko];
      bs_[j] = *(const s16x8*)&Ws1T[(size_t)(wn * 64 + j * 16 + fr) * DD + ko];
    }
#pragma unroll
    for (int i = 0; i < 4; ++i)
#pragma unroll
      for (int j = 0; j < 4; ++j) {
        at[i][j]  = __builtin_amdgcn_mfma_f32_16x16x32_bf16(as_bf(af[i]), as_bf(bt_[j]), at[i][j], 0, 0, 0);
        asx[i][j] = __builtin_amdgcn_mfma_f32_16x16x32_bf16(as_bf(af[i]), as_bf(bs_[j]), asx[i][j], 0, 0, 0);
      }
  }

  // ===================== head 0 epilogue (acc = at) =====================
  {
    float sA[16], qA[16];
#pragma unroll
    for (int k = 0; k < 16; ++k) { sA[k] = 0.f; qA[k] = 0.f; }
#pragma unroll
    for (int i = 0; i < 4; ++i)
#pragma unroll
      for (int j = 0; j < 4; ++j) {
        int col = wn * 64 + j * 16 + fr;
        float bb = bt1[col];
#pragma unroll
        for (int r = 0; r < 4; ++r) {
          float h = gelu_fast(at[i][j][r] + bb);
          at[i][j][r] = h;
          sA[i * 4 + r] += h;
          qA[i * 4 + r] += h * h;
        }
      }
#pragma unroll
    for (int o = 1; o < 16; o <<= 1) {
#pragma unroll
      for (int k = 0; k < 16; ++k) {
        sA[k] += __shfl_xor(sA[k], o);
        qA[k] += __shfl_xor(qA[k], o);
      }
    }
    if (fr == 0) {
#pragma unroll
      for (int i = 0; i < 4; ++i)
#pragma unroll
        for (int r = 0; r < 4; ++r) {
          int row = wm * 64 + i * 16 + fg * 4 + r;
          red[row * 8 + wn]     = sA[i * 4 + r];
          red[row * 8 + 4 + wn] = qA[i * 4 + r];
        }
    }
    __syncthreads();   // also fences the K-loop's last lds_x reads before h-writes
#pragma unroll
    for (int i = 0; i < 4; ++i)
#pragma unroll
      for (int r = 0; r < 4; ++r) {
        int row = wm * 64 + i * 16 + fg * 4 + r;
        float s = red[row * 8 + 0] + red[row * 8 + 1] + red[row * 8 + 2] + red[row * 8 + 3];
        float q = red[row * 8 + 4] + red[row * 8 + 5] + red[row * 8 + 6] + red[row * 8 + 7];
        float mu = s * (1.0f / DD);
        float var = q * (1.0f / DD) - mu * mu;
        float rstd = rsqrtf(var + 1e-5f);
#pragma unroll
        for (int j = 0; j < 4; ++j) {
          int col = wn * 64 + j * 16 + fr;
          float hn = (at[i][j][r] - mu) * rstd * gt[col] + blt[col];
          lds_h[row * 264 + col] = f2bf(hn);
        }
      }
    __syncthreads();                 // red dead; region becomes W2T
    {
      int r = tid >> 5, ch = tid & 31;
      *(uint4*)&lds_w2[r * 264 + ch * 8] = *(const uint4*)&Wt2T[r * 256 + ch * 8];
    }
    __syncthreads();
    {
      f32x4 a1 = f32x4{0.f, 0.f, 0.f, 0.f};
#pragma unroll
      for (int ks = 0; ks < 8; ++ks) {
        s16x8 av = *(const s16x8*)&lds_h[(w * 16 + fr) * 264 + ks * 32 + fg * 8];
        s16x8 bv = *(const s16x8*)&lds_w2[fr * 264 + ks * 32 + fg * 8];
        a1 = __builtin_amdgcn_mfma_f32_16x16x32_bf16(as_bf(av), as_bf(bv), a1, 0, 0, 0);
      }
      if (fr < 8) {
#pragma unroll
        for (int r = 0; r < 4; ++r) lg[(w * 16 + fg * 4 + r) * 8 + fr] = a1[r];
      }
    }
    __syncthreads();
    if (tid < 128) {
      int grow = row0 + tid;
      int mbit = msk[grow];
      float l[6], mx = -1e30f;
#pragma unroll
      for (int c = 0; c < 6; ++c) { l[c] = lg[tid * 8 + c] + bt2[c]; mx = fmaxf(mx, l[c]); }
      float se = 0.0f;
#pragma unroll
      for (int c = 0; c < 6; ++c) se += expf(l[c] - mx);
      float lse = mx + logf(se);
      int t = tgt[grow];
      float lt = 0.0f;
#pragma unroll
      for (int c = 0; c < 6; ++c) lt = (c == t) ? l[c] : lt;
      float contrib = mbit ? (lse - lt) : 0.0f;
      float s = wave_sum(contrib);
      if ((tid & 63) == 0) atomicAdd(&fs[0], s);
    }
    __syncthreads();
  }

  // ===================== head 1 epilogue (acc = asx) =====================
  {
    float sA[16], qA[16];
#pragma unroll
    for (int k = 0; k < 16; ++k) { sA[k] = 0.f; qA[k] = 0.f; }
#pragma unroll
    for (int i = 0; i < 4; ++i)
#pragma unroll
      for (int j = 0; j < 4; ++j) {
        int col = wn * 64 + j * 16 + fr;
        float bb = bs1[col];
#pragma unroll
        for (int r = 0; r < 4; ++r) {
          float h = gelu_fast(asx[i][j][r] + bb);
          asx[i][j][r] = h;
          sA[i * 4 + r] += h;
          qA[i * 4 + r] += h * h;
        }
      }
#pragma unroll
    for (int o = 1; o < 16; o <<= 1) {
#pragma unroll
      for (int k = 0; k < 16; ++k) {
        sA[k] += __shfl_xor(sA[k], o);
        qA[k] += __shfl_xor(qA[k], o);
      }
    }
    if (fr == 0) {
#pragma unroll
      for (int i = 0; i < 4; ++i)
#pragma unroll
        for (int r = 0; r < 4; ++r) {
          int row = wm * 64 + i * 16 + fg * 4 + r;
          red[row * 8 + wn]     = sA[i * 4 + r];
          red[row * 8 + 4 + wn] = qA[i * 4 + r];
        }
    }
    __syncthreads();
#pragma unroll
    for (int i = 0; i < 4; ++i)
#pragma unroll
      for (int r = 0; r < 4; ++r) {
        int row = wm * 64 + i * 16 + fg * 4 + r;
        float s = red[row * 8 + 0] + red[row * 8 + 1] + red[row * 8 + 2] + red[row * 8 + 3];
        float q = red[row * 8 + 4] + red[row * 8 + 5] + red[row * 8 + 6] + red[row * 8 + 7];
        float mu = s * (1.0f / DD);
        float var = q * (1.0f / DD) - mu * mu;
        float rstd = rsqrtf(var + 1e-5f);
#pragma unroll
        for (int j = 0; j < 4; ++j) {
          int col = wn * 64 + j * 16 + fr;
          float hn = (asx[i][j][r] - mu) * rstd * gs[col] + bls[col];
          lds_h[row * 264 + col] = f2bf(hn);
        }
      }
    __syncthreads();
    {
      int r = tid >> 5, ch = tid & 31;
      *(uint4*)&lds_w2[r * 264 + ch * 8] = *(const uint4*)&Ws2T[r * 256 + ch * 8];
    }
    __syncthreads();
    {
      f32x4 a1 = f32x4{0.f, 0.f, 0.f, 0.f};
#pragma unroll
      for (int ks = 0; ks < 8; ++ks) {
        s16x8 av = *(const s16x8*)&lds_h[(w * 16 + fr) * 264 + ks * 32 + fg * 8];
        s16x8 bv = *(const s16x8*)&lds_w2[fr * 264 + ks * 32 + fg * 8];
        a1 = __builtin_amdgcn_mfma_f32_16x16x32_bf16(as_bf(av), as_bf(bv), a1, 0, 0, 0);
      }
      if (fr < 8) {
#pragma unroll
        for (int r = 0; r < 4; ++r) lg[(w * 16 + fg * 4 + r) * 8 + fr] = a1[r];
      }
    }
    __syncthreads();
    if (tid < 128) {
      int grow = row0 + tid;
      int mbit = msk[grow];
      const float* st = stats + (size_t)grow * 8;
      float sse = 0.0f;
#pragma unroll
      for (int c = 0; c < 8; ++c) {
        float d = (lg[tid * 8 + c] + bs2[c]) - st[c];
        sse += d * d;
      }
      float contrib = mbit ? sse : 0.0f;
      float s = wave_sum(contrib);
      if ((tid & 63) == 0) atomicAdd(&fs[1], s);
    }
  }
}

// ---------------- correlation: 64-row i-tiles, ~79 KB LDS ----------------
__global__ __launch_bounds__(512) void k_corr(
    const unsigned short* __restrict__ xbf, const int* __restrict__ msk,
    const float* __restrict__ corr, const unsigned short* __restrict__ WcT,
    const float* __restrict__ bcp, float* __restrict__ fs)
{
  const int tid = threadIdx.x;
  const int b  = blockIdx.x >> 3;
  const int it = blockIdx.x & 7;
  const int i0 = it * 64;
  const int lane = tid & 63, w = tid >> 6;   // 8 waves; wave w owns 32 output cols
  const int wn = w;
  const int fr = lane & 15, fg = lane >> 4;

  __shared__ __align__(16) unsigned short lds_y[64 * 264];   // 33792 B
  __shared__ __align__(16) unsigned short lds_a[64 * 72];    //  9216 B
  __shared__ __align__(16) unsigned short lds_b[256 * 72];   // 36864 B
  __shared__ int ms_i[64];
  __shared__ int ms_j[256];
  __shared__ float red8[8];

  const unsigned short* xb = xbf + (size_t)b * NN * DD;

  // ---- phase Y: y = x[i0..i0+63] @ Wc ----
  f32x4 acc[4][2];
#pragma unroll
  for (int i = 0; i < 4; ++i)
#pragma unroll
    for (int j = 0; j < 2; ++j) acc[i][j] = f32x4{0.f, 0.f, 0.f, 0.f};

  for (int kt = 0; kt < 4; ++kt) {
    __syncthreads();
    {
      int r = tid >> 3, ch = tid & 7;
      *(uint4*)&lds_a[r * 72 + ch * 8] = *(const uint4*)&xb[(size_t)(i0 + r) * DD + kt * 64 + ch * 8];
    }
#pragma unroll
    for (int p = 0; p < 4; ++p) {
      int idx = tid + p * 512;
      int r = idx >> 3, ch = idx & 7;
      *(uint4*)&lds_b[r * 72 + ch * 8] = *(const uint4*)&WcT[r * 256 + kt * 64 + ch * 8];
    }
    __syncthreads();
#pragma unroll
    for (int ks = 0; ks < 2; ++ks) {
      s16x8 af[4], bfv[2];
#pragma unroll
      for (int i = 0; i < 4; ++i)
        af[i] = *(const s16x8*)&lds_a[(i * 16 + fr) * 72 + ks * 32 + fg * 8];
#pragma unroll
      for (int j = 0; j < 2; ++j)
        bfv[j] = *(const s16x8*)&lds_b[(wn * 32 + j * 16 + fr) * 72 + ks * 32 + fg * 8];
#pragma unroll
      for (int i = 0; i < 4; ++i)
#pragma unroll
        for (int j = 0; j < 2; ++j)
          acc[i][j] = __builtin_amdgcn_mfma_f32_16x16x32_bf16(as_bf(af[i]), as_bf(bfv[j]), acc[i][j], 0, 0, 0);
    }
  }
#pragma unroll
  for (int i = 0; i < 4; ++i)
#pragma unroll
    for (int j = 0; j < 2; ++j)
#pragma unroll
      for (int r = 0; r < 4; ++r) {
        int row = i * 16 + fg * 4 + r;
        int col = wn * 32 + j * 16 + fr;
        lds_y[row * 264 + col] = f2bf(acc[i][j][r]);
      }
  if (tid < 64) ms_i[tid] = msk[b * NN + i0 + tid];

  // ---- phase S: scores = y @ x^T, fused tanh + masked MSE ----
  const float bc = bcp[0];
  const float* tb = corr + (size_t)b * NN * NN;
  float sse = 0.0f;

  for (int jc = 0; jc < 2; ++jc) {
    const int j0 = jc * 256;
#pragma unroll
    for (int i = 0; i < 4; ++i)
#pragma unroll
      for (int j = 0; j < 2; ++j) acc[i][j] = f32x4{0.f, 0.f, 0.f, 0.f};

    for (int kt = 0; kt < 4; ++kt) {
      __syncthreads();
#pragma unroll
      for (int p = 0; p < 4; ++p) {
        int idx = tid + p * 512;
        int r = idx >> 3, ch = idx & 7;
        *(uint4*)&lds_b[r * 72 + ch * 8] = *(const uint4*)&xb[(size_t)(j0 + r) * DD + kt * 64 + ch * 8];
      }
      if (kt == 0 && tid < 256) ms_j[tid] = msk[b * NN + j0 + tid];
      __syncthreads();
#pragma unroll
      for (int ks = 0; ks < 2; ++ks) {
        s16x8 af[4], bfv[2];
#pragma unroll
        for (int i = 0; i < 4; ++i)
          af[i] = *(const s16x8*)&lds_y[(i * 16 + fr) * 264 + kt * 64 + ks * 32 + fg * 8];
#pragma unroll
        for (int j = 0; j < 2; ++j)
          bfv[j] = *(const s16x8*)&lds_b[(wn * 32 + j * 16 + fr) * 72 + ks * 32 + fg * 8];
#pragma unroll
        for (int i = 0; i < 4; ++i)
#pragma unroll
          for (int j = 0; j < 2; ++j)
            acc[i][j] = __builtin_amdgcn_mfma_f32_16x16x32_bf16(as_bf(af[i]), as_bf(bfv[j]), acc[i][j], 0, 0, 0);
      }
    }

    // late batched register prefetch of the 32 corr targets for this jc tile
    float tg[4][2][4];
#pragma unroll
    for (int i = 0; i < 4; ++i) {
      int rbase = i0 + i * 16 + fg * 4;
#pragma unroll
      for (int j = 0; j < 2; ++j) {
        int gj = j0 + wn * 32 + j * 16 + fr;
#pragma unroll
        for (int r = 0; r < 4; ++r)
          tg[i][j][r] = tb[(size_t)(rbase + r) * NN + gj];
      }
    }

    // compute epilogue on registers
#pragma unroll
    for (int i = 0; i < 4; ++i) {
      int rbase = i * 16 + fg * 4;
#pragma unroll
      for (int j = 0; j < 2; ++j) {
        int colc = wn * 32 + j * 16 + fr;
        int gj = j0 + colc;
        int mj = ms_j[colc];
#pragma unroll
        for (int r = 0; r < 4; ++r) {
          int gi = i0 + rbase + r;
          float s = acc[i][j][r] + bc;
          float e = __expf(2.0f * s);
          float cv = 1.0f - 2.0f * __builtin_amdgcn_rcpf(e + 1.0f);
          if (gi == gj) cv = 1.0f;
          float d = cv - tg[i][j][r];
          int mb = ms_i[rbase + r] | mj;
          sse += mb ? d * d : 0.0f;
        }
      }
    }
  }

  float s = wave_sum(sse);
  if (lane == 0) red8[w] = s;
  __syncthreads();
  if (tid == 0) {
    float t = 0.f;
#pragma unroll
    for (int i = 0; i < 8; ++i) t += red8[i];
    atomicAdd(&fs[2], t);
  }
}

__global__ void k_final(const float* __restrict__ fs, const int* __restrict__ wsi,
                        float* __restrict__ out) {
  if (threadIdx.x == 0 && blockIdx.x == 0) {
    float cm = (float)wsi[4];
    float c2 = (float)wsi[5];
    out[0] = fs[0] / fmaxf(cm, 1.0f) + fs[1] / fmaxf(8.0f * cm, 1.0f) +
             0.5f * fs[2] / fmaxf(c2, 1.0f);
  }
}

extern "C" void kernel_launch(void* const* d_in, const int* in_sizes, int n_in,
                              void* d_out, int out_size, void* d_ws, size_t ws_size,
                              hipStream_t stream) {
  const float* x     = (const float*)d_in[0];
  const int*   msk   = (const int*)d_in[1];
  const int*   tgt   = (const int*)d_in[2];
  const float* stats = (const float*)d_in[3];
  const float* corr  = (const float*)d_in[4];
  const float* Wt1   = (const float*)d_in[5];
  const float* bt1   = (const float*)d_in[6];
  const float* gt    = (const float*)d_in[7];
  const float* blt   = (const float*)d_in[8];
  const float* Wt2   = (const float*)d_in[9];
  const float* bt2   = (const float*)d_in[10];
  const float* Ws1   = (const float*)d_in[11];
  const float* bs1   = (const float*)d_in[12];
  const float* gs    = (const float*)d_in[13];
  const float* bls   = (const float*)d_in[14];
  const float* Ws2   = (const float*)d_in[15];
  const float* bs2   = (const float*)d_in[16];
  const float* Wc    = (const float*)d_in[17];
  const float* bc    = (const float*)d_in[18];

  float* fs = (float*)d_ws;
  int* wsi  = (int*)d_ws;
  unsigned short* WcT  = (unsigned short*)((char*)d_ws + 256);
  unsigned short* Wt1T = WcT + 65536;
  unsigned short* Ws1T = Wt1T + 65536;
  unsigned short* Wt2T = Ws1T + 65536;
  unsigned short* Ws2T = Wt2T + 4096;
  unsigned short* xbf  = Ws2T + 4096;   // 32 MB; total ws use ~34 MB

  hipLaunchKernelGGL(k_init, dim3(1), dim3(64), 0, stream, wsi);
  hipLaunchKernelGGL(k_counts, dim3(BB), dim3(256), 0, stream, msk, wsi);
  hipLaunchKernelGGL(k_prep, dim3(256), dim3(256), 0, stream,
                     Wc, Wt1, Ws1, Wt2, Ws2, WcT, Wt1T, Ws1T, Wt2T, Ws2T);
  hipLaunchKernelGGL(k_heads, dim3((BB * NN) / 128), dim3(512), 0, stream,
                     x, xbf, msk, tgt, stats, Wt1T, Ws1T, Wt2T, Ws2T,
                     bt1, bs1, gt, gs, blt, bls, bt2, bs2, fs);
  hipLaunchKernelGGL(k_corr, dim3(BB * (NN / 64)), dim3(512), 0, stream,
                     xbf, msk, corr, WcT, bc, fs);
  hipLaunchKernelGGL(k_final, dim3(1), dim3(64), 0, stream, fs, wsi, (float*)d_out);
}